// Round 8
// baseline (685.508 us; speedup 1.0000x reference)
//
#include <hip/hip_runtime.h>
#include <hip/hip_bf16.h>

// ---------------------------------------------------------------------------
// GAT (3 layers) + global mean pool + linear head.
// R8: agg8 8-deep pipelined gather + packed v_pk_fma_f32 math (uint2 bf16-pair
// extraction), agg_h1 rebuilt wave-per-node (barrier-free), 2-pass binned
// scatter.
// ---------------------------------------------------------------------------

#define LRELU(x) ((x) >= 0.f ? (x) : 0.2f * (x))

typedef unsigned short ushort8 __attribute__((ext_vector_type(8)));
typedef unsigned short ushort4v __attribute__((ext_vector_type(4)));
typedef __attribute__((ext_vector_type(8))) short bf16x8;
typedef __attribute__((ext_vector_type(4))) float f32x4;
typedef __attribute__((ext_vector_type(2))) float f32x2;

__device__ __forceinline__ float bf2f(unsigned short u) {
    return __uint_as_float(((unsigned)u) << 16);
}
__device__ __forceinline__ unsigned short f2bf(float f) {
    __hip_bfloat16 b = __float2bfloat16(f);
    return *reinterpret_cast<unsigned short*>(&b);
}
__device__ __forceinline__ void gl_lds16(const unsigned short* g, unsigned short* l) {
    __builtin_amdgcn_global_load_lds((const __attribute__((address_space(1))) void*)g,
                                     (__attribute__((address_space(3))) void*)l, 16, 0, 0);
}

// ---------------- CSR build ----------------

__global__ void deg_kernel(const int* __restrict__ dst, int* __restrict__ deg,
                           int E, int N) {
    int i = blockIdx.x * blockDim.x + threadIdx.x;
    if (i < E) atomicAdd(&deg[dst[i]], 1);
    else if (i < E + N) atomicAdd(&deg[i - E], 1);   // self loop
}

__global__ void scan_kernel(const int* __restrict__ deg, int* __restrict__ rowptr,
                            int n) {
    __shared__ int partial[1024];
    const int tid = threadIdx.x;
    const int chunk = (n + 1023) / 1024;
    const int start = min(tid * chunk, n);
    const int end = min(start + chunk, n);
    int s = 0;
    for (int i = start; i < end; i++) s += deg[i];
    partial[tid] = s;
    __syncthreads();
    for (int o = 1; o < 1024; o <<= 1) {
        int v = (tid >= o) ? partial[tid - o] : 0;
        __syncthreads();
        partial[tid] += v;
        __syncthreads();
    }
    int run = (tid == 0) ? 0 : partial[tid - 1];
    for (int i = start; i < end; i++) { rowptr[i] = run; run += deg[i]; }
    if (tid == 0) rowptr[n] = partial[1023];
}

// Binned scatter: col write region per pass stays L2-resident.
// After all passes rowptr[n] = END of segment n (shifted convention).
__global__ void scatter_col_binned(const int* __restrict__ src, const int* __restrict__ dst,
                                   int* __restrict__ rowptr, int* __restrict__ col,
                                   int E, int N, int lo, int hi) {
    int i = blockIdx.x * blockDim.x + threadIdx.x;
    if (i < E) {
        int d = dst[i];
        if (d < lo || d >= hi) return;
        int pos = atomicAdd(&rowptr[d], 1);
        col[pos] = src[i];
    } else if (i < E + N) {
        int d = i - E;
        if (d < lo || d >= hi) return;
        int pos = atomicAdd(&rowptr[d], 1);
        col[pos] = d;
    }
}

__global__ void expand_dst_kernel(const int* __restrict__ rowptr, int* __restrict__ dstA,
                                  int N) {
    int n = blockIdx.x * blockDim.x + threadIdx.x;
    if (n >= N) return;
    int r0 = (n == 0) ? 0 : rowptr[n - 1];
    int r1 = rowptr[n];
    for (int p = r0; p < r1; p++) dstA[p] = n;
}

__global__ void gstart_kernel(const int* __restrict__ batch, int* __restrict__ gstart,
                              int N, int G) {
    int g = blockIdx.x * blockDim.x + threadIdx.x;
    if (g > G) return;
    int lo = 0, hi = N;
    while (lo < hi) { int mid = (lo + hi) >> 1; if (batch[mid] < g) lo = mid + 1; else hi = mid; }
    gstart[g] = lo;
}

// ---------------- f32 -> bf16 hi/lo split kernels ----------------

__global__ void split_plain_kernel(const float* __restrict__ X, unsigned short* __restrict__ h,
                                   unsigned short* __restrict__ l, int n) {
    int i = blockIdx.x * blockDim.x + threadIdx.x;
    if (i >= n) return;
    float v = X[i];
    unsigned short hb = f2bf(v);
    h[i] = hb;
    l[i] = f2bf(v - bf2f(hb));
}

__global__ void splitT_kernel(const float* __restrict__ W, unsigned short* __restrict__ th,
                              unsigned short* __restrict__ tl, int K, int N) {
    int i = blockIdx.x * blockDim.x + threadIdx.x;
    if (i >= N * K) return;
    int n = i / K, k = i - n * K;
    float v = W[(size_t)k * N + n];
    unsigned short hb = f2bf(v);
    th[i] = hb;
    tl[i] = f2bf(v - bf2f(hb));
}

// ---------------- MFMA split-bf16 GEMM, global_load_lds staging ----------------

template <int BM, int BN, int WM, int WN>
__global__ __launch_bounds__(256)
void gemm_mfma_v2(const unsigned short* __restrict__ Ah, const unsigned short* __restrict__ Al,
                  const unsigned short* __restrict__ Bth, const unsigned short* __restrict__ Btl,
                  unsigned short* __restrict__ Cc, int M, int N, int K) {
    constexpr int BK = 32;
    constexpr int MT = WM / 16, NT = WN / 16;
    constexpr int NWX = BN / WN;
    __shared__ __attribute__((aligned(16))) unsigned short Ha[BM][BK];
    __shared__ __attribute__((aligned(16))) unsigned short La[BM][BK];
    __shared__ __attribute__((aligned(16))) unsigned short Hb[BN][BK];
    __shared__ __attribute__((aligned(16))) unsigned short Lb[BN][BK];
    const int tid = threadIdx.x;
    const int lane = tid & 63;
    const int wave = tid >> 6;
    const int wx = wave % NWX, wy = wave / NWX;
    const int by = blockIdx.y * BM;
    const int bx = blockIdx.x * BN;
    const int r16 = lane & 15, kg = lane >> 4;
    const int srow = lane >> 2, sslot = lane & 3;

    f32x4 acc[MT][NT];
#pragma unroll
    for (int i = 0; i < MT; i++)
#pragma unroll
        for (int j = 0; j < NT; j++) acc[i][j] = (f32x4){0.f, 0.f, 0.f, 0.f};

    for (int k0 = 0; k0 < K; k0 += BK) {
        for (int t = wave; t < BM / 16; t += 4) {
            int gm = by + t * 16 + srow;
            if (gm >= M) gm = M - 1;
            const size_t goff = (size_t)gm * K + k0 + sslot * 8;
            gl_lds16(Ah + goff, &Ha[t * 16][0]);
            gl_lds16(Al + goff, &La[t * 16][0]);
        }
        for (int t = wave; t < BN / 16; t += 4) {
            int gn = bx + t * 16 + srow;
            const size_t goff = (size_t)gn * K + k0 + sslot * 8;
            gl_lds16(Bth + goff, &Hb[t * 16][0]);
            gl_lds16(Btl + goff, &Lb[t * 16][0]);
        }
        __syncthreads();
        bf16x8 bh[NT], bl[NT];
#pragma unroll
        for (int j = 0; j < NT; j++) {
            bh[j] = *(const bf16x8*)&Hb[wx * WN + j * 16 + r16][kg * 8];
            bl[j] = *(const bf16x8*)&Lb[wx * WN + j * 16 + r16][kg * 8];
        }
#pragma unroll
        for (int i = 0; i < MT; i++) {
            bf16x8 ah = *(const bf16x8*)&Ha[wy * WM + i * 16 + r16][kg * 8];
            bf16x8 al2 = *(const bf16x8*)&La[wy * WM + i * 16 + r16][kg * 8];
#pragma unroll
            for (int j = 0; j < NT; j++) {
                acc[i][j] = __builtin_amdgcn_mfma_f32_16x16x32_bf16(ah, bh[j], acc[i][j], 0, 0, 0);
                acc[i][j] = __builtin_amdgcn_mfma_f32_16x16x32_bf16(ah, bl[j], acc[i][j], 0, 0, 0);
                acc[i][j] = __builtin_amdgcn_mfma_f32_16x16x32_bf16(al2, bh[j], acc[i][j], 0, 0, 0);
            }
        }
        __syncthreads();
    }
#pragma unroll
    for (int i = 0; i < MT; i++) {
#pragma unroll
        for (int r = 0; r < 4; r++) {
            int gm = by + wy * WM + i * 16 + kg * 4 + r;
            if (gm >= M) continue;
#pragma unroll
            for (int j = 0; j < NT; j++) {
                int gn = bx + wx * WN + j * 16 + r16;
                Cc[(size_t)gm * N + gn] = f2bf(acc[i][j][r]);
            }
        }
    }
}

// ---------------- per-node attention logits (bf16 h, 16B loads) ----------------

template <int H, int C>
__global__ void al_bf16(const unsigned short* __restrict__ hfeat, const float* __restrict__ a_src,
                        const float* __restrict__ a_dst, float* __restrict__ als,
                        float* __restrict__ ald, int N) {
    int i = blockIdx.x * blockDim.x + threadIdx.x;
    if (i >= N * H) return;
    int n = i / H, h = i % H;
    const unsigned short* hp = hfeat + (size_t)n * H * C + h * C;
    float s1 = 0.f, s2 = 0.f;
    for (int c0 = 0; c0 < C; c0 += 8) {
        ushort8 v = *(const ushort8*)(hp + c0);
#pragma unroll
        for (int k = 0; k < 8; k++) {
            float f = bf2f(v[k]);
            s1 += f * a_src[h * C + c0 + k];
            s2 += f * a_dst[h * C + c0 + k];
        }
    }
    als[i] = s1;
    ald[i] = s2;
}

// ---------------- per-edge softmax numerator ----------------

__global__ void edge_w_pair(const float* __restrict__ als, const float* __restrict__ ald,
                            const int* __restrict__ col, const int* __restrict__ dstA,
                            unsigned int* __restrict__ wts2, int Etot) {
    int i = blockIdx.x * blockDim.x + threadIdx.x;
    if (i >= Etot * 4) return;
    int pos = i >> 2, hp = i & 3;
    int s = col[pos], d = dstA[pos];
    float2 a = *(const float2*)&als[(size_t)s * 8 + hp * 2];
    float2 b = *(const float2*)&ald[(size_t)d * 8 + hp * 2];
    float e0 = a.x + b.x; e0 = LRELU(e0);
    float e1 = a.y + b.y; e1 = LRELU(e1);
    unsigned lo = f2bf(__expf(e0));
    unsigned hi = f2bf(__expf(e1));
    wts2[i] = lo | (hi << 16);
}

__global__ void edge_w_h1(const float* __restrict__ als, const float* __restrict__ ald,
                          const int* __restrict__ col, const int* __restrict__ dstA,
                          unsigned short* __restrict__ wts, int Etot) {
    int i = blockIdx.x * blockDim.x + threadIdx.x;
    if (i >= Etot) return;
    int s = col[i], d = dstA[i];
    float e = als[s] + ald[d];
    e = LRELU(e);
    wts[i] = f2bf(__expf(e));
}

// ---------------- H=8 aggregate: wave-per-node, 8-deep, packed math ----------------

__global__ __launch_bounds__(256)
void gat_agg_w8(const unsigned short* __restrict__ hfeat,
                const unsigned short* __restrict__ wts,   // [pos][8] bf16 bits
                const int* __restrict__ rowptr,           // shifted: rowptr[n] = END
                const int* __restrict__ col,
                const float* __restrict__ bias,
                unsigned short* __restrict__ outH, unsigned short* __restrict__ outL,
                int N) {
    constexpr int CAP = 128;
    const int wid = threadIdx.x >> 6;
    const int lane = threadIdx.x & 63;
    const int n = blockIdx.x * 4 + wid;
    __shared__ float se_all[4][CAP * 8];
    __shared__ int scol_all[4][CAP];
    if (n >= N) return;
    float* se = se_all[wid];
    int* scol = scol_all[wid];

    const int r0 = (n == 0) ? 0 : rowptr[n - 1];
    const int deg = rowptr[n] - r0;
    const int dh8 = deg * 8;
    const size_t wbase = (size_t)r0 * 8;
    const int dcap = min(deg, CAP);

    // stage col -> LDS (coalesced)
    for (int j = lane; j < dcap; j += 64) scol[j] = col[r0 + j];

    // ---- pass A: weights -> se + per-head sums in registers ----
    float p0 = 0.f, p1 = 0.f, p2 = 0.f, p3 = 0.f, p4 = 0.f, p5 = 0.f, p6 = 0.f, p7 = 0.f;
    for (int base = 0; base < dh8; base += 512) {
        int idx = base + lane * 8;
        if (idx < dh8) {
            ushort8 v = *(const ushort8*)&wts[wbase + idx];
            float f0 = bf2f(v[0]), f1 = bf2f(v[1]), f2 = bf2f(v[2]), f3 = bf2f(v[3]);
            float f4 = bf2f(v[4]), f5 = bf2f(v[5]), f6 = bf2f(v[6]), f7 = bf2f(v[7]);
            p0 += f0; p1 += f1; p2 += f2; p3 += f3;
            p4 += f4; p5 += f5; p6 += f6; p7 += f7;
            if (idx < CAP * 8) {
                *(float4*)&se[idx] = (float4){f0, f1, f2, f3};
                *(float4*)&se[idx + 4] = (float4){f4, f5, f6, f7};
            }
        }
    }
#pragma unroll
    for (int m = 1; m < 64; m <<= 1) {
        p0 += __shfl_xor(p0, m); p1 += __shfl_xor(p1, m);
        p2 += __shfl_xor(p2, m); p3 += __shfl_xor(p3, m);
        p4 += __shfl_xor(p4, m); p5 += __shfl_xor(p5, m);
        p6 += __shfl_xor(p6, m); p7 += __shfl_xor(p7, m);
    }
    const int q = lane >> 3;                 // this lane's head in pass B
    float S = (q == 0) ? p0 : (q == 1) ? p1 : (q == 2) ? p2 : (q == 3) ? p3
            : (q == 4) ? p4 : (q == 5) ? p5 : (q == 6) ? p6 : p7;
    const float sinv = 1.0f / S;

    // ---- pass B: 8-deep gather, packed f32x2 accumulate ----
    const int cb = lane * 4;                 // this lane's 4 output cols
    f32x2 acc01 = {0.f, 0.f}, acc23 = {0.f, 0.f};
    int j = 0;
    for (; j + 7 < dcap; j += 8) {
        int s[8];
#pragma unroll
        for (int u = 0; u < 8; u++) s[u] = __builtin_amdgcn_readfirstlane(scol[j + u]);
        uint2 d[8];
#pragma unroll
        for (int u = 0; u < 8; u++) d[u] = *(const uint2*)(hfeat + (size_t)s[u] * 256 + cb);
#pragma unroll
        for (int u = 0; u < 8; u++) {
            float w = se[(j + u) * 8 + q];
            f32x2 wp = {w, w};
            acc01 += (f32x2){__uint_as_float(d[u].x << 16),
                             __uint_as_float(d[u].x & 0xffff0000u)} * wp;
            acc23 += (f32x2){__uint_as_float(d[u].y << 16),
                             __uint_as_float(d[u].y & 0xffff0000u)} * wp;
        }
    }
    for (; j < dcap; j++) {
        int s0 = __builtin_amdgcn_readfirstlane(scol[j]);
        uint2 d = *(const uint2*)(hfeat + (size_t)s0 * 256 + cb);
        float w = se[j * 8 + q];
        f32x2 wp = {w, w};
        acc01 += (f32x2){__uint_as_float(d.x << 16), __uint_as_float(d.x & 0xffff0000u)} * wp;
        acc23 += (f32x2){__uint_as_float(d.y << 16), __uint_as_float(d.y & 0xffff0000u)} * wp;
    }
    for (; j < deg; j++) {                   // deg > CAP fallback (essentially never)
        int s0 = col[r0 + j];
        float w = bf2f(wts[wbase + (size_t)j * 8 + q]);
        uint2 d = *(const uint2*)(hfeat + (size_t)s0 * 256 + cb);
        f32x2 wp = {w, w};
        acc01 += (f32x2){__uint_as_float(d.x << 16), __uint_as_float(d.x & 0xffff0000u)} * wp;
        acc23 += (f32x2){__uint_as_float(d.y << 16), __uint_as_float(d.y & 0xffff0000u)} * wp;
    }

    // ---- epilogue: normalize + bias + relu + hi/lo split store ----
    float4 b4 = *(const float4*)&bias[cb];
    float o0 = fmaxf(acc01.x * sinv + b4.x, 0.f);
    float o1 = fmaxf(acc01.y * sinv + b4.y, 0.f);
    float o2 = fmaxf(acc23.x * sinv + b4.z, 0.f);
    float o3 = fmaxf(acc23.y * sinv + b4.w, 0.f);
    unsigned short h0 = f2bf(o0), h1 = f2bf(o1), h2 = f2bf(o2), h3 = f2bf(o3);
    const size_t ob = (size_t)n * 256 + cb;
    *(ushort4v*)&outH[ob] = (ushort4v){h0, h1, h2, h3};
    *(ushort4v*)&outL[ob] = (ushort4v){f2bf(o0 - bf2f(h0)), f2bf(o1 - bf2f(h1)),
                                       f2bf(o2 - bf2f(h2)), f2bf(o3 - bf2f(h3))};
}

// ---------------- H=1 aggregate: wave-per-node, 8 lanes/edge ----------------
// slot = lane>>3 (edge within 8-group), ch = lane&7 (4-col chunk of the 32-col
// row). Cross-slot shfl reduce at the end; lanes of slot 0 store float4.

__global__ __launch_bounds__(256)
void gat_agg_h1w(const unsigned short* __restrict__ hfeat,
                 const unsigned short* __restrict__ wts,
                 const int* __restrict__ rowptr, const int* __restrict__ col,
                 const float* __restrict__ bias, float* __restrict__ out, int N) {
    constexpr int CAP = 256;
    const int wid = threadIdx.x >> 6;
    const int lane = threadIdx.x & 63;
    const int n = blockIdx.x * 4 + wid;
    __shared__ float sw_all[4][CAP];
    __shared__ int scol_all[4][CAP];
    if (n >= N) return;
    float* sw = sw_all[wid];
    int* scol = scol_all[wid];

    const int r0 = (n == 0) ? 0 : rowptr[n - 1];
    const int deg = rowptr[n] - r0;
    const int dcap = min(deg, CAP);

    float lsum = 0.f;
    for (int idx = lane; idx < deg; idx += 64) {
        float v = bf2f(wts[r0 + idx]);
        if (idx < CAP) { sw[idx] = v; scol[idx] = col[r0 + idx]; }
        lsum += v;
    }
#pragma unroll
    for (int m = 1; m < 64; m <<= 1) lsum += __shfl_xor(lsum, m);
    const float sinv = 1.0f / lsum;

    const int slot = lane >> 3, ch = lane & 7;
    f32x2 acc01 = {0.f, 0.f}, acc23 = {0.f, 0.f};
    for (int j = 0; j < dcap; j += 8) {
        int e = j + slot;
        int ec = min(e, dcap - 1);
        int s = scol[ec];
        float w = (e < dcap) ? sw[ec] : 0.f;
        uint2 d = *(const uint2*)(hfeat + (size_t)s * 32 + ch * 4);
        f32x2 wp = {w, w};
        acc01 += (f32x2){__uint_as_float(d.x << 16), __uint_as_float(d.x & 0xffff0000u)} * wp;
        acc23 += (f32x2){__uint_as_float(d.y << 16), __uint_as_float(d.y & 0xffff0000u)} * wp;
    }
    for (int j = CAP; j < deg; j += 8) {     // deg > CAP fallback
        int e = j + slot;
        int ec = min(e, deg - 1);
        int s = col[r0 + ec];
        float w = (e < deg) ? bf2f(wts[r0 + ec]) : 0.f;
        uint2 d = *(const uint2*)(hfeat + (size_t)s * 32 + ch * 4);
        f32x2 wp = {w, w};
        acc01 += (f32x2){__uint_as_float(d.x << 16), __uint_as_float(d.x & 0xffff0000u)} * wp;
        acc23 += (f32x2){__uint_as_float(d.y << 16), __uint_as_float(d.y & 0xffff0000u)} * wp;
    }
    // reduce across slots (lane bits 3..5)
#pragma unroll
    for (int m = 8; m < 64; m <<= 1) {
        acc01.x += __shfl_xor(acc01.x, m);
        acc01.y += __shfl_xor(acc01.y, m);
        acc23.x += __shfl_xor(acc23.x, m);
        acc23.y += __shfl_xor(acc23.y, m);
    }
    if (slot == 0) {
        float4 b4 = *(const float4*)&bias[ch * 4];
        float4 o;
        o.x = acc01.x * sinv + b4.x;
        o.y = acc01.y * sinv + b4.y;
        o.z = acc23.x * sinv + b4.z;
        o.w = acc23.y * sinv + b4.w;
        *(float4*)&out[(size_t)n * 32 + ch * 4] = o;
    }
}

// ---------------- fused pool + head (sorted batch, no atomics) ----------------

__global__ __launch_bounds__(256)
void pool_final_kernel(const float* __restrict__ h, const int* __restrict__ gstart,
                       const float* __restrict__ lin_w, const float* __restrict__ lin_b,
                       float* __restrict__ out) {
    const int g = blockIdx.x;
    const int tid = threadIdx.x;
    const int n0 = gstart[g], n1 = gstart[g + 1];
    const int r = tid >> 5, c = tid & 31;
    __shared__ float pp[4][32];
    __shared__ float pm[32];
    float acc = 0.f;
    for (int n = n0 + r; n < n1; n += 8) acc += h[(size_t)n * 32 + c];
    acc += __shfl_xor(acc, 32);
    if ((tid & 63) < 32) pp[tid >> 6][c] = acc;
    __syncthreads();
    if (tid < 32) {
        float s = pp[0][tid] + pp[1][tid] + pp[2][tid] + pp[3][tid];
        pm[tid] = s / fmaxf((float)(n1 - n0), 1.f);
    }
    __syncthreads();
    if (tid < 64) {
        float a = lin_b[tid];
#pragma unroll 8
        for (int cc = 0; cc < 32; cc++) a += pm[cc] * lin_w[cc * 64 + tid];
        out[(size_t)g * 64 + tid] = a;
    }
}

// ---------------- launch ----------------

extern "C" void kernel_launch(void* const* d_in, const int* in_sizes, int n_in,
                              void* d_out, int out_size, void* d_ws, size_t ws_size,
                              hipStream_t stream) {
    const float* x     = (const float*)d_in[0];
    const int*   ei    = (const int*)d_in[1];
    const int*   batch = (const int*)d_in[2];
    const float* W0    = (const float*)d_in[3];
    const float* a_s0  = (const float*)d_in[4];
    const float* a_d0  = (const float*)d_in[5];
    const float* b0    = (const float*)d_in[6];
    const float* W1    = (const float*)d_in[7];
    const float* a_s1  = (const float*)d_in[8];
    const float* a_d1  = (const float*)d_in[9];
    const float* b1    = (const float*)d_in[10];
    const float* W2    = (const float*)d_in[11];
    const float* a_s2  = (const float*)d_in[12];
    const float* a_d2  = (const float*)d_in[13];
    const float* b2    = (const float*)d_in[14];
    const float* lin_w = (const float*)d_in[15];
    const float* lin_b = (const float*)d_in[16];

    const int N = in_sizes[0] / 128;   // 50000
    const int E = in_sizes[1] / 2;     // 1600000
    const int G = 256;
    const int Etot = E + N;
    const int* src = ei;
    const int* dst = ei + E;

    char* w = (char*)d_ws;
    size_t off = 0;
    auto alloc = [&](size_t bytes) -> void* {
        void* p = (void*)(w + off);
        off += (bytes + 255) & ~(size_t)255;
        return p;
    };
    int* deg    = (int*)alloc((size_t)N * 4);
    int* rowptr = (int*)alloc((size_t)(N + 1) * 4);
    int* colA   = (int*)alloc((size_t)Etot * 4);
    int* dstA   = (int*)alloc((size_t)Etot * 4);
    int* gstart = (int*)alloc((size_t)(G + 1) * 4);
    float* als  = (float*)alloc((size_t)N * 8 * 4);
    float* ald  = (float*)alloc((size_t)N * 8 * 4);
    unsigned short* hb  = (unsigned short*)alloc((size_t)N * 256 * 2);
    unsigned short* wts = (unsigned short*)alloc((size_t)Etot * 8 * 2);
    unsigned short* g0h = (unsigned short*)alloc((size_t)N * 256 * 2);
    unsigned short* g0l = (unsigned short*)alloc((size_t)N * 256 * 2);
    float* out2 = (float*)alloc((size_t)N * 32 * 4);
    unsigned short* w0h = (unsigned short*)alloc((size_t)128 * 256 * 2);
    unsigned short* w0l = (unsigned short*)alloc((size_t)128 * 256 * 2);
    unsigned short* w1h = (unsigned short*)alloc((size_t)256 * 256 * 2);
    unsigned short* w1l = (unsigned short*)alloc((size_t)256 * 256 * 2);
    unsigned short* w2h = (unsigned short*)alloc((size_t)256 * 32 * 2);
    unsigned short* w2l = (unsigned short*)alloc((size_t)256 * 32 * 2);
    unsigned short* xh = g0h;
    unsigned short* xl = g0h + (size_t)N * 128;

    hipMemsetAsync(deg, 0, (size_t)N * 4, stream);

    deg_kernel<<<(Etot + 255) / 256, 256, 0, stream>>>(dst, deg, E, N);
    scan_kernel<<<1, 1024, 0, stream>>>(deg, rowptr, N);
    for (int p = 0; p < 2; p++) {
        int lo = (int)((size_t)N * p / 2);
        int hi = (int)((size_t)N * (p + 1) / 2);
        scatter_col_binned<<<(Etot + 255) / 256, 256, 0, stream>>>(src, dst, rowptr, colA, E, N, lo, hi);
    }
    expand_dst_kernel<<<(N + 255) / 256, 256, 0, stream>>>(rowptr, dstA, N);
    gstart_kernel<<<2, 256, 0, stream>>>(batch, gstart, N, G);

    split_plain_kernel<<<(N * 128 + 255) / 256, 256, 0, stream>>>(x, xh, xl, N * 128);
    splitT_kernel<<<(128 * 256 + 255) / 256, 256, 0, stream>>>(W0, w0h, w0l, 128, 256);
    splitT_kernel<<<(256 * 256 + 255) / 256, 256, 0, stream>>>(W1, w1h, w1l, 256, 256);
    splitT_kernel<<<(256 * 32 + 255) / 256, 256, 0, stream>>>(W2, w2h, w2l, 256, 32);

    const int MB = (N + 127) / 128;

    // layer 0: K=128
    gemm_mfma_v2<128, 128, 64, 64><<<dim3(2, MB), 256, 0, stream>>>(xh, xl, w0h, w0l, hb, N, 256, 128);
    al_bf16<8, 32><<<(N * 8 + 255) / 256, 256, 0, stream>>>(hb, a_s0, a_d0, als, ald, N);
    edge_w_pair<<<((size_t)Etot * 4 + 255) / 256, 256, 0, stream>>>(als, ald, colA, dstA, (unsigned int*)wts, Etot);
    gat_agg_w8<<<(N + 3) / 4, 256, 0, stream>>>(hb, wts, rowptr, colA, b0, g0h, g0l, N);

    // layer 1: K=256
    gemm_mfma_v2<128, 128, 64, 64><<<dim3(2, MB), 256, 0, stream>>>(g0h, g0l, w1h, w1l, hb, N, 256, 256);
    al_bf16<8, 32><<<(N * 8 + 255) / 256, 256, 0, stream>>>(hb, a_s1, a_d1, als, ald, N);
    edge_w_pair<<<((size_t)Etot * 4 + 255) / 256, 256, 0, stream>>>(als, ald, colA, dstA, (unsigned int*)wts, Etot);
    gat_agg_w8<<<(N + 3) / 4, 256, 0, stream>>>(hb, wts, rowptr, colA, b1, g0h, g0l, N);

    // layer 2: heads=1, C=32, K=256
    gemm_mfma_v2<128, 32, 32, 32><<<dim3(1, MB), 256, 0, stream>>>(g0h, g0l, w2h, w2l, hb, N, 32, 256);
    al_bf16<1, 32><<<(N + 255) / 256, 256, 0, stream>>>(hb, a_s2, a_d2, als, ald, N);
    edge_w_h1<<<(Etot + 255) / 256, 256, 0, stream>>>(als, ald, colA, dstA, wts, Etot);
    gat_agg_h1w<<<(N + 3) / 4, 256, 0, stream>>>(hb, wts, rowptr, colA, b2, out2, N);

    // fused pool + head
    pool_final_kernel<<<G, 256, 0, stream>>>(out2, gstart, lin_w, lin_b, (float*)d_out);
}